// Round 1
// 6218.626 us; speedup vs baseline: 2.2154x; 2.2154x over previous
//
#include <hip/hip_runtime.h>
#include <hip/hip_bf16.h>
#include <math.h>

// ---------------------------------------------------------------------------
// GPT-style transformer forward, fp32. Round 2: tiled flash-attention.
// L=4, H=12, HD=64, D=768, V=50257, B=1, T=2048
// Round-1 profile: k_attn (serial per-key online softmax, 1 wave/row) was
// 2.3 ms/layer = 9.2 ms of 13.8 ms — latency-bound (25 GB/s HBM, 49% VALU).
// Replaced with 64x64-tile flash attention structured like k_gemm.
// ---------------------------------------------------------------------------

__global__ __launch_bounds__(256) void k_embed(const int* __restrict__ ids,
                                               const float* __restrict__ emb,
                                               float* __restrict__ x,
                                               int T, int D) {
  int t = blockIdx.x;
  int id = ids[t];
  float neg_log = -logf(10000.0f) / (float)D;
  for (int d = threadIdx.x; d < D; d += 256) {
    float freq = expf((float)(d & ~1) * neg_log);
    float ang = (float)t * freq;
    float pe = (d & 1) ? cosf(ang) : sinf(ang);
    x[(size_t)t * D + d] = emb[(size_t)id * D + d] + pe;
  }
}

__global__ __launch_bounds__(256) void k_layernorm(const float* __restrict__ x,
                                                   const float* __restrict__ g,
                                                   const float* __restrict__ b,
                                                   float* __restrict__ y,
                                                   int D) {
  int t = blockIdx.x;
  const float* xr = x + (size_t)t * D;
  __shared__ float red[256];
  float s = 0.f;
  for (int d = threadIdx.x; d < D; d += 256) s += xr[d];
  red[threadIdx.x] = s;
  __syncthreads();
  for (int st = 128; st > 0; st >>= 1) {
    if (threadIdx.x < st) red[threadIdx.x] += red[threadIdx.x + st];
    __syncthreads();
  }
  float mean = red[0] / (float)D;
  __syncthreads();
  float s2 = 0.f;
  for (int d = threadIdx.x; d < D; d += 256) {
    float u = xr[d] - mean;
    s2 += u * u;
  }
  red[threadIdx.x] = s2;
  __syncthreads();
  for (int st = 128; st > 0; st >>= 1) {
    if (threadIdx.x < st) red[threadIdx.x] += red[threadIdx.x + st];
    __syncthreads();
  }
  float rstd = rsqrtf(red[0] / (float)D + 1e-5f);
  float* yr = y + (size_t)t * D;
  for (int d = threadIdx.x; d < D; d += 256)
    yr[d] = (xr[d] - mean) * rstd * g[d] + b[d];
}

__device__ __forceinline__ float gelu_exact(float v) {
  return 0.5f * v * (1.0f + erff(v * 0.70710678118654752f));
}

// C[M,N] = A[M,K] @ B[N,K]^T + bias[N]  (+res / gelu per mode)
// mode 0: bias only; mode 1: + res[M,N]; mode 2: gelu(acc+bias)
__global__ __launch_bounds__(256) void k_gemm(const float* __restrict__ A,
                                              const float* __restrict__ B,
                                              const float* __restrict__ bias,
                                              const float* __restrict__ res,
                                              float* __restrict__ C,
                                              int M, int N, int K, int mode) {
  __shared__ float As[16][64];
  __shared__ float Bs[16][64];
  int tid = threadIdx.x;
  int tx = tid & 15, ty = tid >> 4;
  int m0 = blockIdx.y << 6, n0 = blockIdx.x << 6;
  int ar = tid >> 2, ac = (tid & 3) << 2;  // loader: row 0..63, k-offset {0,4,8,12}
  float acc[4][4] = {};

  for (int kt = 0; kt < K; kt += 16) {
    float4 av = *(const float4*)(A + (size_t)(m0 + ar) * K + kt + ac);
    float4 bv;
    int brow = n0 + ar;
    if (brow < N)
      bv = *(const float4*)(B + (size_t)brow * K + kt + ac);
    else
      bv = make_float4(0.f, 0.f, 0.f, 0.f);
    As[ac + 0][ar] = av.x; As[ac + 1][ar] = av.y;
    As[ac + 2][ar] = av.z; As[ac + 3][ar] = av.w;
    Bs[ac + 0][ar] = bv.x; Bs[ac + 1][ar] = bv.y;
    Bs[ac + 2][ar] = bv.z; Bs[ac + 3][ar] = bv.w;
    __syncthreads();
#pragma unroll
    for (int k = 0; k < 16; ++k) {
      float4 a = *(const float4*)&As[k][ty << 2];
      float4 b = *(const float4*)&Bs[k][tx << 2];
      acc[0][0] += a.x * b.x; acc[0][1] += a.x * b.y; acc[0][2] += a.x * b.z; acc[0][3] += a.x * b.w;
      acc[1][0] += a.y * b.x; acc[1][1] += a.y * b.y; acc[1][2] += a.y * b.z; acc[1][3] += a.y * b.w;
      acc[2][0] += a.z * b.x; acc[2][1] += a.z * b.y; acc[2][2] += a.z * b.z; acc[2][3] += a.z * b.w;
      acc[3][0] += a.w * b.x; acc[3][1] += a.w * b.y; acc[3][2] += a.w * b.z; acc[3][3] += a.w * b.w;
    }
    __syncthreads();
  }

  int colBase = n0 + (tx << 2);
  if (n0 + 64 <= N) {
    float4 bsv = *(const float4*)(bias + colBase);
#pragma unroll
    for (int i = 0; i < 4; ++i) {
      int row = m0 + (ty << 2) + i;
      float4 r = make_float4(acc[i][0] + bsv.x, acc[i][1] + bsv.y,
                             acc[i][2] + bsv.z, acc[i][3] + bsv.w);
      if (mode == 1) {
        float4 rv = *(const float4*)(res + (size_t)row * N + colBase);
        r.x += rv.x; r.y += rv.y; r.z += rv.z; r.w += rv.w;
      } else if (mode == 2) {
        r.x = gelu_exact(r.x); r.y = gelu_exact(r.y);
        r.z = gelu_exact(r.z); r.w = gelu_exact(r.w);
      }
      *(float4*)(C + (size_t)row * N + colBase) = r;
    }
  } else {
#pragma unroll
    for (int i = 0; i < 4; ++i) {
      int row = m0 + (ty << 2) + i;
#pragma unroll
      for (int j = 0; j < 4; ++j) {
        int col = colBase + j;
        if (col < N) {
          float vvv = acc[i][j] + bias[col];
          if (mode == 1) vvv += res[(size_t)row * N + col];
          else if (mode == 2) vvv = gelu_exact(vvv);
          C[(size_t)row * N + col] = vvv;
        }
      }
    }
  }
}

// ---------------------------------------------------------------------------
// Tiled flash attention. Grid: (T/64, H); block 256 = 4 waves.
// Each block: one head h, one 64-row query tile. Iterates 64-key tiles
// 0..qt with online softmax. Per k-tile: S = Qs @ Ks^T (register-tiled GEMM
// from LDS, identical microstructure to k_gemm), shuffle-reduce row max/sum
// across the 16 tx lanes, P written back to LDS (aliases K buffer),
// O += P @ V as second register-tiled GEMM.
// LDS: 3 x 64x68 fp32 = 52.2 KB -> 3 blocks/CU.
// qt = gridDim.x-1-blockIdx.x so the heaviest (long-diagonal) blocks launch
// first (causal triangle load balance).
// ---------------------------------------------------------------------------
__global__ __launch_bounds__(256) void k_flash(const float* __restrict__ q,
                                               const float* __restrict__ k,
                                               const float* __restrict__ v,
                                               float* __restrict__ ctx,
                                               int T, int D, float scale) {
  __shared__ float Qs[64][68];   // Q^T: [d][q], pre-scaled
  __shared__ float KPs[64][68];  // K^T: [d][s] during QK; P^T: [s][q] during PV
  __shared__ float Vs[64][68];   // V:   [s][d]
  int tid = threadIdx.x;
  int tx = tid & 15, ty = tid >> 4;
  int qt = gridDim.x - 1 - blockIdx.x;  // big tiles first
  int q0 = qt << 6;
  int hoff = blockIdx.y << 6;

  // load Q tile transposed, folding in the softmax scale
  {
    int row = tid >> 2;          // 0..63 (q row)
    int col = (tid & 3) << 4;    // 0,16,32,48
    const float* src = q + (size_t)(q0 + row) * D + hoff + col;
#pragma unroll
    for (int i = 0; i < 4; ++i) {
      float4 a = *(const float4*)(src + (i << 2));
      Qs[col + (i << 2) + 0][row] = a.x * scale;
      Qs[col + (i << 2) + 1][row] = a.y * scale;
      Qs[col + (i << 2) + 2][row] = a.z * scale;
      Qs[col + (i << 2) + 3][row] = a.w * scale;
    }
  }

  float m[4] = {-1e30f, -1e30f, -1e30f, -1e30f};
  float l[4] = {0.f, 0.f, 0.f, 0.f};
  float po[4][4] = {};

  for (int st = 0; st <= qt; ++st) {
    int s0 = st << 6;
    __syncthreads();  // previous PV readers of KPs/Vs done (also covers Qs, st=0)
    {
      int row = tid >> 2;
      int col = (tid & 3) << 4;
      const float* ksrc = k + (size_t)(s0 + row) * D + hoff + col;
      const float* vsrc = v + (size_t)(s0 + row) * D + hoff + col;
#pragma unroll
      for (int i = 0; i < 4; ++i) {
        float4 a = *(const float4*)(ksrc + (i << 2));
        KPs[col + (i << 2) + 0][row] = a.x;
        KPs[col + (i << 2) + 1][row] = a.y;
        KPs[col + (i << 2) + 2][row] = a.z;
        KPs[col + (i << 2) + 3][row] = a.w;
        *(float4*)&Vs[row][col + (i << 2)] = *(const float4*)(vsrc + (i << 2));
      }
    }
    __syncthreads();

    // S[q][s] tile: q rows ty*4.., s cols tx*4..
    float s[4][4] = {};
#pragma unroll 8
    for (int kk = 0; kk < 64; ++kk) {
      float4 a = *(const float4*)&Qs[kk][ty << 2];
      float4 b = *(const float4*)&KPs[kk][tx << 2];
      s[0][0] += a.x * b.x; s[0][1] += a.x * b.y; s[0][2] += a.x * b.z; s[0][3] += a.x * b.w;
      s[1][0] += a.y * b.x; s[1][1] += a.y * b.y; s[1][2] += a.y * b.z; s[1][3] += a.y * b.w;
      s[2][0] += a.z * b.x; s[2][1] += a.z * b.y; s[2][2] += a.z * b.z; s[2][3] += a.z * b.w;
      s[3][0] += a.w * b.x; s[3][1] += a.w * b.y; s[3][2] += a.w * b.z; s[3][3] += a.w * b.w;
    }

    if (st == qt) {  // causal mask only on the diagonal tile
#pragma unroll
      for (int qi = 0; qi < 4; ++qi) {
        int qrow = (ty << 2) + qi;
#pragma unroll
        for (int si = 0; si < 4; ++si) {
          if ((tx << 2) + si > qrow) s[qi][si] = -1e30f;
        }
      }
    }

    // online softmax, per q-row (reduce across the 16 tx lanes: lane bits 0-3)
    float alpha[4];
#pragma unroll
    for (int qi = 0; qi < 4; ++qi) {
      float rmax = fmaxf(fmaxf(s[qi][0], s[qi][1]), fmaxf(s[qi][2], s[qi][3]));
      rmax = fmaxf(rmax, __shfl_xor(rmax, 1, 64));
      rmax = fmaxf(rmax, __shfl_xor(rmax, 2, 64));
      rmax = fmaxf(rmax, __shfl_xor(rmax, 4, 64));
      rmax = fmaxf(rmax, __shfl_xor(rmax, 8, 64));
      float mn = fmaxf(m[qi], rmax);
      alpha[qi] = __expf(m[qi] - mn);
      m[qi] = mn;
      float rsum = 0.f;
#pragma unroll
      for (int si = 0; si < 4; ++si) {
        float p = __expf(s[qi][si] - mn);
        s[qi][si] = p;
        rsum += p;
      }
      rsum += __shfl_xor(rsum, 1, 64);
      rsum += __shfl_xor(rsum, 2, 64);
      rsum += __shfl_xor(rsum, 4, 64);
      rsum += __shfl_xor(rsum, 8, 64);
      l[qi] = l[qi] * alpha[qi] + rsum;
      po[qi][0] *= alpha[qi]; po[qi][1] *= alpha[qi];
      po[qi][2] *= alpha[qi]; po[qi][3] *= alpha[qi];
    }

    __syncthreads();  // all QK reads of KPs done before overwrite with P^T
#pragma unroll
    for (int si = 0; si < 4; ++si) {
      float4 p4 = make_float4(s[0][si], s[1][si], s[2][si], s[3][si]);
      *(float4*)&KPs[(tx << 2) + si][ty << 2] = p4;  // P^T[s][q]
    }
    __syncthreads();

    // O[q][d] += P @ V: q rows ty*4.., d cols tx*4..
#pragma unroll 8
    for (int kk = 0; kk < 64; ++kk) {
      float4 a = *(const float4*)&KPs[kk][ty << 2];
      float4 b = *(const float4*)&Vs[kk][tx << 2];
      po[0][0] += a.x * b.x; po[0][1] += a.x * b.y; po[0][2] += a.x * b.z; po[0][3] += a.x * b.w;
      po[1][0] += a.y * b.x; po[1][1] += a.y * b.y; po[1][2] += a.y * b.z; po[1][3] += a.y * b.w;
      po[2][0] += a.z * b.x; po[2][1] += a.z * b.y; po[2][2] += a.z * b.z; po[2][3] += a.z * b.w;
      po[3][0] += a.w * b.x; po[3][1] += a.w * b.y; po[3][2] += a.w * b.z; po[3][3] += a.w * b.w;
    }
  }

#pragma unroll
  for (int qi = 0; qi < 4; ++qi) {
    float inv = 1.0f / l[qi];
    float4 r = make_float4(po[qi][0] * inv, po[qi][1] * inv,
                           po[qi][2] * inv, po[qi][3] * inv);
    *(float4*)(ctx + (size_t)(q0 + (ty << 2) + qi) * D + hoff + (tx << 2)) = r;
  }
}

extern "C" void kernel_launch(void* const* d_in, const int* in_sizes, int n_in,
                              void* d_out, int out_size, void* d_ws, size_t ws_size,
                              hipStream_t stream) {
  const int T = 2048, D = 768, H = 12, L = 4, V = 50257, D4 = 3072;
  const size_t td = (size_t)T * D;

  const int* ids      = (const int*)d_in[0];
  const float* emb    = (const float*)d_in[1];
  const float* lm_bias= (const float*)d_in[2];
  const float* ln1_g  = (const float*)d_in[3];
  const float* ln1_b  = (const float*)d_in[4];
  const float* ln2_g  = (const float*)d_in[5];
  const float* ln2_b  = (const float*)d_in[6];
  const float* Wq     = (const float*)d_in[7];
  const float* bq     = (const float*)d_in[8];
  const float* Wk     = (const float*)d_in[9];
  const float* bk     = (const float*)d_in[10];
  const float* Wv     = (const float*)d_in[11];
  const float* bv     = (const float*)d_in[12];
  const float* Wo     = (const float*)d_in[13];
  const float* bo     = (const float*)d_in[14];
  const float* W1     = (const float*)d_in[15];
  const float* b1     = (const float*)d_in[16];
  const float* W2     = (const float*)d_in[17];
  const float* b2     = (const float*)d_in[18];
  const float* lnf_g  = (const float*)d_in[19];
  const float* lnf_b  = (const float*)d_in[20];
  float* out = (float*)d_out;

  // Scratch layout (ws-size-safe, see round-1 note):
  //   x, xn           -> d_ws          (2*T*D fp32 = 12.6 MB)
  //   q,k,v,ctx / MLP -> tail of d_out (4*T*D fp32 = 25.2 MB) unless d_ws is
  //                      big enough. Tail scratch is dead before the final
  //                      LM-head GEMM overwrites d_out; its input xn is in
  //                      d_ws, so no read/write race.
  float* x  = (float*)d_ws;
  float* xn = x + td;
  float* qb;
  if (ws_size >= (size_t)6 * td * sizeof(float)) {
    qb = xn + td;
  } else {
    qb = out + ((size_t)out_size - 4 * td);  // out_size*4B aligned tail
  }
  float* kb = qb + td;
  float* vb = kb + td;
  float* cb = vb + td;
  float* hb = qb;  // [T, 4D] aliases q,k,v,ctx (dead during MLP)

  dim3 blk(256);
  k_embed<<<T, blk, 0, stream>>>(ids, emb, x, T, D);

  for (int l = 0; l < L; ++l) {
    k_layernorm<<<T, blk, 0, stream>>>(x, ln1_g + l * D, ln1_b + l * D, xn, D);

    dim3 gqkv(D / 64, T / 64);
    k_gemm<<<gqkv, blk, 0, stream>>>(xn, Wq + (size_t)l * D * D, bq + l * D, nullptr, qb, T, D, D, 0);
    k_gemm<<<gqkv, blk, 0, stream>>>(xn, Wk + (size_t)l * D * D, bk + l * D, nullptr, kb, T, D, D, 0);
    k_gemm<<<gqkv, blk, 0, stream>>>(xn, Wv + (size_t)l * D * D, bv + l * D, nullptr, vb, T, D, D, 0);

    dim3 ga(T / 64, H);
    k_flash<<<ga, blk, 0, stream>>>(qb, kb, vb, cb, T, D, 0.125f);

    k_gemm<<<gqkv, blk, 0, stream>>>(cb, Wo + (size_t)l * D * D, bo + l * D, x, x, T, D, D, 1);

    k_layernorm<<<T, blk, 0, stream>>>(x, ln2_g + l * D, ln2_b + l * D, xn, D);

    dim3 g1(D4 / 64, T / 64);
    k_gemm<<<g1, blk, 0, stream>>>(xn, W1 + (size_t)l * D4 * D, b1 + l * D4, nullptr, hb, T, D4, D, 2);

    dim3 g2(D / 64, T / 64);
    k_gemm<<<g2, blk, 0, stream>>>(hb, W2 + (size_t)l * D * D4, b2 + l * D, x, x, T, D, D4, 1);
  }

  k_layernorm<<<T, blk, 0, stream>>>(x, lnf_g, lnf_b, xn, D);

  dim3 gl((V + 63) / 64, T / 64);
  k_gemm<<<gl, blk, 0, stream>>>(xn, emb, lm_bias, nullptr, out, T, V, D, 0);
}

// Round 4
// 3402.834 us; speedup vs baseline: 4.0486x; 1.8275x over previous
//
#include <hip/hip_runtime.h>
#include <hip/hip_bf16.h>
#include <math.h>

// ---------------------------------------------------------------------------
// GPT-style transformer forward. Round 4: bf16-MFMA GEMMs (retry, hardened).
// L=4, H=12, HD=64, D=768, V=50257, B=1, T=2048
// Rounds 2-3 died with "container failed twice" (no profile). Audit found one
// latent hazard: the d_out TAIL scratch fallback assumed out_size is an
// element count; if it is bytes, the pointer is ~1.2 GB OOB and staging
// writes could kill the container. Fallback scratch now uses the FRONT of
// d_out (in-bounds under either unit convention; dead before the LM-head
// GEMM, whose inputs xn/emb do not alias it). k_mm itself unchanged.
// Round-1 profile: all GEMMs on fp32 VALU (MfmaUtil=0.0, ~68 TF of 157 TF
// vector ceiling); LM head alone 2.31 ms. Matrix pipe (2.5 PF bf16) idle ->
// convert A/B to bf16 in staging, MFMA 16x16x32, fp32 accumulate.
// ---------------------------------------------------------------------------

typedef __attribute__((ext_vector_type(8))) short bf16x8;
typedef __attribute__((ext_vector_type(4))) float f32x4;

__global__ __launch_bounds__(256) void k_embed(const int* __restrict__ ids,
                                               const float* __restrict__ emb,
                                               float* __restrict__ x,
                                               int T, int D) {
  int t = blockIdx.x;
  int id = ids[t];
  float neg_log = -logf(10000.0f) / (float)D;
  for (int d = threadIdx.x; d < D; d += 256) {
    float freq = expf((float)(d & ~1) * neg_log);
    float ang = (float)t * freq;
    float pe = (d & 1) ? cosf(ang) : sinf(ang);
    x[(size_t)t * D + d] = emb[(size_t)id * D + d] + pe;
  }
}

__global__ __launch_bounds__(256) void k_layernorm(const float* __restrict__ x,
                                                   const float* __restrict__ g,
                                                   const float* __restrict__ b,
                                                   float* __restrict__ y,
                                                   int D) {
  int t = blockIdx.x;
  const float* xr = x + (size_t)t * D;
  __shared__ float red[256];
  float s = 0.f;
  for (int d = threadIdx.x; d < D; d += 256) s += xr[d];
  red[threadIdx.x] = s;
  __syncthreads();
  for (int st = 128; st > 0; st >>= 1) {
    if (threadIdx.x < st) red[threadIdx.x] += red[threadIdx.x + st];
    __syncthreads();
  }
  float mean = red[0] / (float)D;
  __syncthreads();
  float s2 = 0.f;
  for (int d = threadIdx.x; d < D; d += 256) {
    float u = xr[d] - mean;
    s2 += u * u;
  }
  red[threadIdx.x] = s2;
  __syncthreads();
  for (int st = 128; st > 0; st >>= 1) {
    if (threadIdx.x < st) red[threadIdx.x] += red[threadIdx.x + st];
    __syncthreads();
  }
  float rstd = rsqrtf(red[0] / (float)D + 1e-5f);
  float* yr = y + (size_t)t * D;
  for (int d = threadIdx.x; d < D; d += 256)
    yr[d] = (xr[d] - mean) * rstd * g[d] + b[d];
}

__device__ __forceinline__ float gelu_exact(float v) {
  return 0.5f * v * (1.0f + erff(v * 0.70710678118654752f));
}

__device__ __forceinline__ unsigned short f2bf(float f) {
  // round-to-nearest-even bf16
  unsigned u = __float_as_uint(f);
  u += 0x7FFFu + ((u >> 16) & 1u);
  return (unsigned short)(u >> 16);
}

// ---------------------------------------------------------------------------
// C[M,N] = A[M,K] @ B[N,K]^T + bias[N]   (+res / gelu per mode)
// mode 0: bias only; mode 1: + res[M,N]; mode 2: gelu(acc+bias)
// bf16 MFMA 16x16x32, fp32 accumulate. 128x128 tile, BK=32, 256 thr = 4 waves,
// each wave owns a 64x64 quadrant (4x4 fragments of 16x16).
// LDS per matrix: 4 k-slot planes of [128 rows][8 bf16] (2048 B) padded to
// 2080 B so plane stride is 32 B mod 128 -> both ds_write_b128 (staging) and
// ds_read_b128 (fragments) hit all 32 banks per 8-lane group: conflict-free
// (round-1 k_gemm logged 2.3e8 SQ_LDS_BANK_CONFLICT).
// Next K-tile global loads are issued before the MFMA loop (overlap).
// M must be a multiple of 128 (true: M=T=2048); N,K arbitrary mult. of 32.
// ---------------------------------------------------------------------------
__global__ __launch_bounds__(256) void k_mm(const float* __restrict__ A,
                                            const float* __restrict__ B,
                                            const float* __restrict__ bias,
                                            const float* __restrict__ res,
                                            float* __restrict__ C,
                                            int M, int N, int K, int mode) {
  constexpr int PLANE = 2080;     // 128*16 + 32 pad
  constexpr int MATS = 4 * PLANE; // 8320 per matrix
  __shared__ alignas(16) unsigned char smem[2 * MATS];

  const int tid = threadIdx.x;
  const int lane = tid & 63;
  const int wid = tid >> 6;
  const int wr = wid >> 1, wc = wid & 1;
  const int m0 = blockIdx.y << 7, n0 = blockIdx.x << 7;

  // staging role: threads 0-127 stage A rows m0.., threads 128-255 stage B rows n0..
  const int mat = tid >> 7;
  const int ts = tid & 127;
  const int kslot = ts & 3;      // which 8-wide k slot
  const int r0 = ts >> 2;        // 0..31, rows r0, r0+32, r0+64, r0+96
  const float* gbase = mat ? B : A;
  const int gr0 = (mat ? n0 : m0) + r0;
  unsigned char* wbase = smem + mat * MATS + kslot * PLANE;

  // fragment read bases
  const int lr = lane & 15, lk = lane >> 4;
  const unsigned char* ard = smem + lk * PLANE + (wr * 64 + lr) * 16;
  const unsigned char* brd = smem + MATS + lk * PLANE + (wc * 64 + lr) * 16;

  f32x4 acc[4][4] = {};
  float4 g[4][2];

  const int NK = K >> 5;

  // prologue: load K-tile 0 (B rows beyond N -> zeros, stay zero all K-steps)
#pragma unroll
  for (int i = 0; i < 4; ++i) {
    int grow = gr0 + (i << 5);
    if (mat == 0 || grow < N) {
      const float* p = gbase + (size_t)grow * K + (kslot << 3);
      g[i][0] = *(const float4*)p;
      g[i][1] = *(const float4*)(p + 4);
    } else {
      g[i][0] = make_float4(0.f, 0.f, 0.f, 0.f);
      g[i][1] = make_float4(0.f, 0.f, 0.f, 0.f);
    }
  }

  for (int kt = 0; kt < NK; ++kt) {
    if (kt) __syncthreads();  // previous MFMA reads done before overwrite
#pragma unroll
    for (int i = 0; i < 4; ++i) {
      union { bf16x8 v; unsigned short u[8]; } r;
      r.u[0] = f2bf(g[i][0].x); r.u[1] = f2bf(g[i][0].y);
      r.u[2] = f2bf(g[i][0].z); r.u[3] = f2bf(g[i][0].w);
      r.u[4] = f2bf(g[i][1].x); r.u[5] = f2bf(g[i][1].y);
      r.u[6] = f2bf(g[i][1].z); r.u[7] = f2bf(g[i][1].w);
      *(bf16x8*)(wbase + (r0 + (i << 5)) * 16) = r.v;
    }
    __syncthreads();

    // issue next K-tile loads now; they overlap the MFMA work below
    if (kt + 1 < NK) {
      int ko = ((kt + 1) << 5) + (kslot << 3);
#pragma unroll
      for (int i = 0; i < 4; ++i) {
        int grow = gr0 + (i << 5);
        if (mat == 0 || grow < N) {
          const float* p = gbase + (size_t)grow * K + ko;
          g[i][0] = *(const float4*)p;
          g[i][1] = *(const float4*)(p + 4);
        }
      }
    }

    bf16x8 af[4], bf[4];
#pragma unroll
    for (int f = 0; f < 4; ++f) {
      af[f] = *(const bf16x8*)(ard + f * 256);   // +16 rows per fragment
      bf[f] = *(const bf16x8*)(brd + f * 256);
    }
#pragma unroll
    for (int fm = 0; fm < 4; ++fm)
#pragma unroll
      for (int fn = 0; fn < 4; ++fn)
        acc[fm][fn] = __builtin_amdgcn_mfma_f32_16x16x32_bf16(
            af[fm], bf[fn], acc[fm][fn], 0, 0, 0);
  }

  // epilogue: C/D layout col = lane&15, row = (lane>>4)*4 + reg
  const int orow0 = m0 + wr * 64 + (lk << 2);
  const int ocol0 = n0 + wc * 64 + lr;
#pragma unroll
  for (int fn = 0; fn < 4; ++fn) {
    int col = ocol0 + fn * 16;
    if (col >= N) continue;
    float bv = bias[col];
#pragma unroll
    for (int fm = 0; fm < 4; ++fm) {
#pragma unroll
      for (int j = 0; j < 4; ++j) {
        int row = orow0 + fm * 16 + j;
        float vvv = acc[fm][fn][j] + bv;
        if (mode == 1) vvv += res[(size_t)row * N + col];
        else if (mode == 2) vvv = gelu_exact(vvv);
        C[(size_t)row * N + col] = vvv;
      }
    }
  }
}

// ---------------------------------------------------------------------------
// Tiled flash attention (fp32 VALU) — unchanged from round 1 (verified).
// Grid: (T/64, H); block 256 = 4 waves.
// ---------------------------------------------------------------------------
__global__ __launch_bounds__(256) void k_flash(const float* __restrict__ q,
                                               const float* __restrict__ k,
                                               const float* __restrict__ v,
                                               float* __restrict__ ctx,
                                               int T, int D, float scale) {
  __shared__ float Qs[64][68];   // Q^T: [d][q], pre-scaled
  __shared__ float KPs[64][68];  // K^T: [d][s] during QK; P^T: [s][q] during PV
  __shared__ float Vs[64][68];   // V:   [s][d]
  int tid = threadIdx.x;
  int tx = tid & 15, ty = tid >> 4;
  int qt = gridDim.x - 1 - blockIdx.x;  // big tiles first
  int q0 = qt << 6;
  int hoff = blockIdx.y << 6;

  {
    int row = tid >> 2;
    int col = (tid & 3) << 4;
    const float* src = q + (size_t)(q0 + row) * D + hoff + col;
#pragma unroll
    for (int i = 0; i < 4; ++i) {
      float4 a = *(const float4*)(src + (i << 2));
      Qs[col + (i << 2) + 0][row] = a.x * scale;
      Qs[col + (i << 2) + 1][row] = a.y * scale;
      Qs[col + (i << 2) + 2][row] = a.z * scale;
      Qs[col + (i << 2) + 3][row] = a.w * scale;
    }
  }

  float m[4] = {-1e30f, -1e30f, -1e30f, -1e30f};
  float l[4] = {0.f, 0.f, 0.f, 0.f};
  float po[4][4] = {};

  for (int st = 0; st <= qt; ++st) {
    int s0 = st << 6;
    __syncthreads();
    {
      int row = tid >> 2;
      int col = (tid & 3) << 4;
      const float* ksrc = k + (size_t)(s0 + row) * D + hoff + col;
      const float* vsrc = v + (size_t)(s0 + row) * D + hoff + col;
#pragma unroll
      for (int i = 0; i < 4; ++i) {
        float4 a = *(const float4*)(ksrc + (i << 2));
        KPs[col + (i << 2) + 0][row] = a.x;
        KPs[col + (i << 2) + 1][row] = a.y;
        KPs[col + (i << 2) + 2][row] = a.z;
        KPs[col + (i << 2) + 3][row] = a.w;
        *(float4*)&Vs[row][col + (i << 2)] = *(const float4*)(vsrc + (i << 2));
      }
    }
    __syncthreads();

    float s[4][4] = {};
#pragma unroll 8
    for (int kk = 0; kk < 64; ++kk) {
      float4 a = *(const float4*)&Qs[kk][ty << 2];
      float4 b = *(const float4*)&KPs[kk][tx << 2];
      s[0][0] += a.x * b.x; s[0][1] += a.x * b.y; s[0][2] += a.x * b.z; s[0][3] += a.x * b.w;
      s[1][0] += a.y * b.x; s[1][1] += a.y * b.y; s[1][2] += a.y * b.z; s[1][3] += a.y * b.w;
      s[2][0] += a.z * b.x; s[2][1] += a.z * b.y; s[2][2] += a.z * b.z; s[2][3] += a.z * b.w;
      s[3][0] += a.w * b.x; s[3][1] += a.w * b.y; s[3][2] += a.w * b.z; s[3][3] += a.w * b.w;
    }

    if (st == qt) {
#pragma unroll
      for (int qi = 0; qi < 4; ++qi) {
        int qrow = (ty << 2) + qi;
#pragma unroll
        for (int si = 0; si < 4; ++si) {
          if ((tx << 2) + si > qrow) s[qi][si] = -1e30f;
        }
      }
    }

    float alpha[4];
#pragma unroll
    for (int qi = 0; qi < 4; ++qi) {
      float rmax = fmaxf(fmaxf(s[qi][0], s[qi][1]), fmaxf(s[qi][2], s[qi][3]));
      rmax = fmaxf(rmax, __shfl_xor(rmax, 1, 64));
      rmax = fmaxf(rmax, __shfl_xor(rmax, 2, 64));
      rmax = fmaxf(rmax, __shfl_xor(rmax, 4, 64));
      rmax = fmaxf(rmax, __shfl_xor(rmax, 8, 64));
      float mn = fmaxf(m[qi], rmax);
      alpha[qi] = __expf(m[qi] - mn);
      m[qi] = mn;
      float rsum = 0.f;
#pragma unroll
      for (int si = 0; si < 4; ++si) {
        float p = __expf(s[qi][si] - mn);
        s[qi][si] = p;
        rsum += p;
      }
      rsum += __shfl_xor(rsum, 1, 64);
      rsum += __shfl_xor(rsum, 2, 64);
      rsum += __shfl_xor(rsum, 4, 64);
      rsum += __shfl_xor(rsum, 8, 64);
      l[qi] = l[qi] * alpha[qi] + rsum;
      po[qi][0] *= alpha[qi]; po[qi][1] *= alpha[qi];
      po[qi][2] *= alpha[qi]; po[qi][3] *= alpha[qi];
    }

    __syncthreads();
#pragma unroll
    for (int si = 0; si < 4; ++si) {
      float4 p4 = make_float4(s[0][si], s[1][si], s[2][si], s[3][si]);
      *(float4*)&KPs[(tx << 2) + si][ty << 2] = p4;
    }
    __syncthreads();

#pragma unroll 8
    for (int kk = 0; kk < 64; ++kk) {
      float4 a = *(const float4*)&KPs[kk][ty << 2];
      float4 b = *(const float4*)&Vs[kk][tx << 2];
      po[0][0] += a.x * b.x; po[0][1] += a.x * b.y; po[0][2] += a.x * b.z; po[0][3] += a.x * b.w;
      po[1][0] += a.y * b.x; po[1][1] += a.y * b.y; po[1][2] += a.y * b.z; po[1][3] += a.y * b.w;
      po[2][0] += a.z * b.x; po[2][1] += a.z * b.y; po[2][2] += a.z * b.z; po[2][3] += a.z * b.w;
      po[3][0] += a.w * b.x; po[3][1] += a.w * b.y; po[3][2] += a.w * b.z; po[3][3] += a.w * b.w;
    }
  }

#pragma unroll
  for (int qi = 0; qi < 4; ++qi) {
    float inv = 1.0f / l[qi];
    float4 r = make_float4(po[qi][0] * inv, po[qi][1] * inv,
                           po[qi][2] * inv, po[qi][3] * inv);
    *(float4*)(ctx + (size_t)(q0 + (ty << 2) + qi) * D + hoff + (tx << 2)) = r;
  }
}

extern "C" void kernel_launch(void* const* d_in, const int* in_sizes, int n_in,
                              void* d_out, int out_size, void* d_ws, size_t ws_size,
                              hipStream_t stream) {
  const int T = 2048, D = 768, H = 12, L = 4, V = 50257, D4 = 3072;
  const size_t td = (size_t)T * D;

  const int* ids      = (const int*)d_in[0];
  const float* emb    = (const float*)d_in[1];
  const float* lm_bias= (const float*)d_in[2];
  const float* ln1_g  = (const float*)d_in[3];
  const float* ln1_b  = (const float*)d_in[4];
  const float* ln2_g  = (const float*)d_in[5];
  const float* ln2_b  = (const float*)d_in[6];
  const float* Wq     = (const float*)d_in[7];
  const float* bq     = (const float*)d_in[8];
  const float* Wk     = (const float*)d_in[9];
  const float* bk     = (const float*)d_in[10];
  const float* Wv     = (const float*)d_in[11];
  const float* bv     = (const float*)d_in[12];
  const float* Wo     = (const float*)d_in[13];
  const float* bo     = (const float*)d_in[14];
  const float* W1     = (const float*)d_in[15];
  const float* b1     = (const float*)d_in[16];
  const float* W2     = (const float*)d_in[17];
  const float* b2     = (const float*)d_in[18];
  const float* lnf_g  = (const float*)d_in[19];
  const float* lnf_b  = (const float*)d_in[20];
  float* out = (float*)d_out;

  // Scratch layout:
  //   x, xn           -> d_ws (2*T*D fp32 = 12.6 MB; ws always holds these)
  //   q,k,v,ctx / MLP -> d_ws if it fits 6*T*D fp32 (37.75 MB); otherwise the
  //                      FRONT of d_out (4*T*D fp32 = 25.2 MB << T*V fp32 =
  //                      412 MB, in-bounds whether out_size is bytes or
  //                      elements). That scratch is dead before the LM-head
  //                      GEMM (sole writer of out; reads xn in d_ws and emb).
  float* x  = (float*)d_ws;
  float* xn = x + td;
  float* qb;
  if (ws_size >= (size_t)6 * td * sizeof(float)) {
    qb = xn + td;
  } else {
    qb = out;  // front of d_out (round-4 hardening; was tail w/ unit-dependent math)
  }
  float* kb = qb + td;
  float* vb = kb + td;
  float* cb = vb + td;
  float* hb = qb;  // [T, 4D] aliases q,k,v,ctx (dead during MLP)

  dim3 blk(256);
  k_embed<<<T, blk, 0, stream>>>(ids, emb, x, T, D);

  for (int l = 0; l < L; ++l) {
    k_layernorm<<<T, blk, 0, stream>>>(x, ln1_g + l * D, ln1_b + l * D, xn, D);

    dim3 gqkv(D / 128, T / 128);
    k_mm<<<gqkv, blk, 0, stream>>>(xn, Wq + (size_t)l * D * D, bq + l * D, nullptr, qb, T, D, D, 0);
    k_mm<<<gqkv, blk, 0, stream>>>(xn, Wk + (size_t)l * D * D, bk + l * D, nullptr, kb, T, D, D, 0);
    k_mm<<<gqkv, blk, 0, stream>>>(xn, Wv + (size_t)l * D * D, bv + l * D, nullptr, vb, T, D, D, 0);

    dim3 ga(T / 64, H);
    k_flash<<<ga, blk, 0, stream>>>(qb, kb, vb, cb, T, D, 0.125f);

    k_mm<<<gqkv, blk, 0, stream>>>(cb, Wo + (size_t)l * D * D, bo + l * D, x, x, T, D, D, 1);

    k_layernorm<<<T, blk, 0, stream>>>(x, ln2_g + l * D, ln2_b + l * D, xn, D);

    dim3 g1(D4 / 128, T / 128);
    k_mm<<<g1, blk, 0, stream>>>(xn, W1 + (size_t)l * D4 * D, b1 + l * D4, nullptr, hb, T, D4, D, 2);

    dim3 g2(D / 128, T / 128);
    k_mm<<<g2, blk, 0, stream>>>(hb, W2 + (size_t)l * D * D4, b2 + l * D, x, x, T, D, D4, 1);
  }

  k_layernorm<<<T, blk, 0, stream>>>(x, lnf_g, lnf_b, xn, D);

  dim3 gl((V + 127) / 128, T / 128);
  k_mm<<<gl, blk, 0, stream>>>(xn, emb, lm_bias, nullptr, out, T, V, D, 0);
}

// Round 5
// 3095.262 us; speedup vs baseline: 4.4509x; 1.0994x over previous
//
#include <hip/hip_runtime.h>
#include <hip/hip_bf16.h>
#include <math.h>

// ---------------------------------------------------------------------------
// GPT-style transformer forward. Round 5: XCD-swizzled k_mm + fused QKV.
// L=4, H=12, HD=64, D=768, V=50257, B=1, T=2048
// Round-4 profile: LM-head k_mm 550 us, FETCH 1.25 GB = 8x emb(154 MB) ->
// every XCD's private L2 re-fetches B (grid x-fastest scatters the 16
// m-blocks of each B-panel across XCDs). Fix: 1-D grid + bijective XCD
// swizzle, logical order n-panel-major / m-fastest, so one XCD owns all 16
// m-blocks of a panel (panel = 393 KB, L2-resident, HBM-fetched once).
// Also: QKV fused into one GEMM (3x96-block launches -> 1x288) writing an
// interleaved [T,2304] buffer; k_flash takes a qkv row-stride.
// ---------------------------------------------------------------------------

typedef __attribute__((ext_vector_type(8))) short bf16x8;
typedef __attribute__((ext_vector_type(4))) float f32x4;

__global__ __launch_bounds__(256) void k_embed(const int* __restrict__ ids,
                                               const float* __restrict__ emb,
                                               float* __restrict__ x,
                                               int T, int D) {
  int t = blockIdx.x;
  int id = ids[t];
  float neg_log = -logf(10000.0f) / (float)D;
  for (int d = threadIdx.x; d < D; d += 256) {
    float freq = expf((float)(d & ~1) * neg_log);
    float ang = (float)t * freq;
    float pe = (d & 1) ? cosf(ang) : sinf(ang);
    x[(size_t)t * D + d] = emb[(size_t)id * D + d] + pe;
  }
}

__global__ __launch_bounds__(256) void k_layernorm(const float* __restrict__ x,
                                                   const float* __restrict__ g,
                                                   const float* __restrict__ b,
                                                   float* __restrict__ y,
                                                   int D) {
  int t = blockIdx.x;
  const float* xr = x + (size_t)t * D;
  __shared__ float red[256];
  float s = 0.f;
  for (int d = threadIdx.x; d < D; d += 256) s += xr[d];
  red[threadIdx.x] = s;
  __syncthreads();
  for (int st = 128; st > 0; st >>= 1) {
    if (threadIdx.x < st) red[threadIdx.x] += red[threadIdx.x + st];
    __syncthreads();
  }
  float mean = red[0] / (float)D;
  __syncthreads();
  float s2 = 0.f;
  for (int d = threadIdx.x; d < D; d += 256) {
    float u = xr[d] - mean;
    s2 += u * u;
  }
  red[threadIdx.x] = s2;
  __syncthreads();
  for (int st = 128; st > 0; st >>= 1) {
    if (threadIdx.x < st) red[threadIdx.x] += red[threadIdx.x + st];
    __syncthreads();
  }
  float rstd = rsqrtf(red[0] / (float)D + 1e-5f);
  float* yr = y + (size_t)t * D;
  for (int d = threadIdx.x; d < D; d += 256)
    yr[d] = (xr[d] - mean) * rstd * g[d] + b[d];
}

__device__ __forceinline__ float gelu_exact(float v) {
  return 0.5f * v * (1.0f + erff(v * 0.70710678118654752f));
}

__device__ __forceinline__ unsigned short f2bf(float f) {
  // round-to-nearest-even bf16
  unsigned u = __float_as_uint(f);
  u += 0x7FFFu + ((u >> 16) & 1u);
  return (unsigned short)(u >> 16);
}

// Bijective XCD swizzle (m204 formula): dispatch id -> logical id such that
// XCD c (= id%8 under round-robin dispatch) gets a contiguous logical chunk.
__device__ __forceinline__ int xcd_swizzle(int orig, int nwg) {
  int xcd = orig & 7, lid = orig >> 3;
  int q8 = nwg >> 3, r8 = nwg & 7;
  return (xcd < r8 ? xcd * (q8 + 1) : r8 * (q8 + 1) + (xcd - r8) * q8) + lid;
}

// ---------------------------------------------------------------------------
// C[M,N] = A[M,K] @ B[N,K]^T + bias[N]   (+res / gelu per mode)
// mode 0: bias only; mode 1: + res[M,N]; mode 2: gelu(acc+bias)
// bf16 MFMA 16x16x32, fp32 accumulate. 128x128 tile, BK=32, 256 thr = 4 waves,
// each wave owns a 64x64 quadrant (4x4 fragments of 16x16).
// 1-D grid (nbx*nby blocks), XCD-swizzled, n-panel-major / m-fastest so each
// XCD keeps one B panel L2-resident for all 16 m-blocks.
// ---------------------------------------------------------------------------
__global__ __launch_bounds__(256) void k_mm(const float* __restrict__ A,
                                            const float* __restrict__ B,
                                            const float* __restrict__ bias,
                                            const float* __restrict__ res,
                                            float* __restrict__ C,
                                            int M, int N, int K, int mode) {
  constexpr int PLANE = 2080;     // 128*16 + 32 pad
  constexpr int MATS = 4 * PLANE; // 8320 per matrix
  __shared__ alignas(16) unsigned char smem[2 * MATS];

  const int nbx = (N + 127) >> 7;
  const int nby = M >> 7;
  const int swz = xcd_swizzle(blockIdx.x, nbx * nby);
  const int nb = swz / nby;        // n panel (major)
  const int mb = swz - nb * nby;   // m fastest
  const int m0 = mb << 7, n0 = nb << 7;

  const int tid = threadIdx.x;
  const int lane = tid & 63;
  const int wid = tid >> 6;
  const int wr = wid >> 1, wc = wid & 1;

  // staging role: threads 0-127 stage A rows m0.., threads 128-255 stage B rows n0..
  const int mat = tid >> 7;
  const int ts = tid & 127;
  const int kslot = ts & 3;      // which 8-wide k slot
  const int r0 = ts >> 2;        // 0..31, rows r0, r0+32, r0+64, r0+96
  const float* gbase = mat ? B : A;
  const int gr0 = (mat ? n0 : m0) + r0;
  unsigned char* wbase = smem + mat * MATS + kslot * PLANE;

  // fragment read bases
  const int lr = lane & 15, lk = lane >> 4;
  const unsigned char* ard = smem + lk * PLANE + (wr * 64 + lr) * 16;
  const unsigned char* brd = smem + MATS + lk * PLANE + (wc * 64 + lr) * 16;

  f32x4 acc[4][4] = {};
  float4 g[4][2];

  const int NK = K >> 5;

  // prologue: load K-tile 0 (B rows beyond N -> zeros, stay zero all K-steps)
#pragma unroll
  for (int i = 0; i < 4; ++i) {
    int grow = gr0 + (i << 5);
    if (mat == 0 || grow < N) {
      const float* p = gbase + (size_t)grow * K + (kslot << 3);
      g[i][0] = *(const float4*)p;
      g[i][1] = *(const float4*)(p + 4);
    } else {
      g[i][0] = make_float4(0.f, 0.f, 0.f, 0.f);
      g[i][1] = make_float4(0.f, 0.f, 0.f, 0.f);
    }
  }

  for (int kt = 0; kt < NK; ++kt) {
    if (kt) __syncthreads();  // previous MFMA reads done before overwrite
#pragma unroll
    for (int i = 0; i < 4; ++i) {
      union { bf16x8 v; unsigned short u[8]; } r;
      r.u[0] = f2bf(g[i][0].x); r.u[1] = f2bf(g[i][0].y);
      r.u[2] = f2bf(g[i][0].z); r.u[3] = f2bf(g[i][0].w);
      r.u[4] = f2bf(g[i][1].x); r.u[5] = f2bf(g[i][1].y);
      r.u[6] = f2bf(g[i][1].z); r.u[7] = f2bf(g[i][1].w);
      *(bf16x8*)(wbase + (r0 + (i << 5)) * 16) = r.v;
    }
    __syncthreads();

    // issue next K-tile loads now; they overlap the MFMA work below
    if (kt + 1 < NK) {
      int ko = ((kt + 1) << 5) + (kslot << 3);
#pragma unroll
      for (int i = 0; i < 4; ++i) {
        int grow = gr0 + (i << 5);
        if (mat == 0 || grow < N) {
          const float* p = gbase + (size_t)grow * K + ko;
          g[i][0] = *(const float4*)p;
          g[i][1] = *(const float4*)(p + 4);
        }
      }
    }

    bf16x8 af[4], bf[4];
#pragma unroll
    for (int f = 0; f < 4; ++f) {
      af[f] = *(const bf16x8*)(ard + f * 256);   // +16 rows per fragment
      bf[f] = *(const bf16x8*)(brd + f * 256);
    }
#pragma unroll
    for (int fm = 0; fm < 4; ++fm)
#pragma unroll
      for (int fn = 0; fn < 4; ++fn)
        acc[fm][fn] = __builtin_amdgcn_mfma_f32_16x16x32_bf16(
            af[fm], bf[fn], acc[fm][fn], 0, 0, 0);
  }

  // epilogue: C/D layout col = lane&15, row = (lane>>4)*4 + reg
  const int orow0 = m0 + wr * 64 + (lk << 2);
  const int ocol0 = n0 + wc * 64 + lr;
#pragma unroll
  for (int fn = 0; fn < 4; ++fn) {
    int col = ocol0 + fn * 16;
    if (col >= N) continue;
    float bv = bias[col];
#pragma unroll
    for (int fm = 0; fm < 4; ++fm) {
#pragma unroll
      for (int j = 0; j < 4; ++j) {
        int row = orow0 + fm * 16 + j;
        float vvv = acc[fm][fn][j] + bv;
        if (mode == 1) vvv += res[(size_t)row * N + col];
        else if (mode == 2) vvv = gelu_exact(vvv);
        C[(size_t)row * N + col] = vvv;
      }
    }
  }
}

// ---------------------------------------------------------------------------
// Fused QKV GEMM: C[M, 2304] = xn @ [Wq|Wk|Wv]^T + [bq|bk|bv].
// Same structure as k_mm; per-block weight select (768 % 128 == 0 so a
// 128-col tile never straddles the q/k/v boundary). No N guards (2304%128==0).
// ---------------------------------------------------------------------------
__global__ __launch_bounds__(256) void k_mmqkv(const float* __restrict__ A,
                                               const float* __restrict__ Wq,
                                               const float* __restrict__ Wk,
                                               const float* __restrict__ Wv,
                                               const float* __restrict__ bq,
                                               const float* __restrict__ bk,
                                               const float* __restrict__ bv,
                                               float* __restrict__ C,
                                               int M, int K) {
  constexpr int PLANE = 2080;
  constexpr int MATS = 4 * PLANE;
  constexpr int NTOT = 2304;
  __shared__ alignas(16) unsigned char smem[2 * MATS];

  const int nbx = NTOT >> 7;  // 18
  const int nby = M >> 7;     // 16
  const int swz = xcd_swizzle(blockIdx.x, nbx * nby);
  const int nb = swz / nby;
  const int mb = swz - nb * nby;
  const int m0 = mb << 7, n0 = nb << 7;

  const int sel = n0 / 768;
  const float* B = sel == 0 ? Wq : (sel == 1 ? Wk : Wv);
  const float* bias = sel == 0 ? bq : (sel == 1 ? bk : bv);
  const int nloc = n0 - sel * 768;

  const int tid = threadIdx.x;
  const int lane = tid & 63;
  const int wid = tid >> 6;
  const int wr = wid >> 1, wc = wid & 1;

  const int mat = tid >> 7;
  const int ts = tid & 127;
  const int kslot = ts & 3;
  const int r0 = ts >> 2;
  const float* gbase = mat ? B : A;
  const int gr0 = (mat ? nloc : m0) + r0;
  unsigned char* wbase = smem + mat * MATS + kslot * PLANE;

  const int lr = lane & 15, lk = lane >> 4;
  const unsigned char* ard = smem + lk * PLANE + (wr * 64 + lr) * 16;
  const unsigned char* brd = smem + MATS + lk * PLANE + (wc * 64 + lr) * 16;

  f32x4 acc[4][4] = {};
  float4 g[4][2];

  const int NK = K >> 5;

#pragma unroll
  for (int i = 0; i < 4; ++i) {
    const float* p = gbase + (size_t)(gr0 + (i << 5)) * K + (kslot << 3);
    g[i][0] = *(const float4*)p;
    g[i][1] = *(const float4*)(p + 4);
  }

  for (int kt = 0; kt < NK; ++kt) {
    if (kt) __syncthreads();
#pragma unroll
    for (int i = 0; i < 4; ++i) {
      union { bf16x8 v; unsigned short u[8]; } r;
      r.u[0] = f2bf(g[i][0].x); r.u[1] = f2bf(g[i][0].y);
      r.u[2] = f2bf(g[i][0].z); r.u[3] = f2bf(g[i][0].w);
      r.u[4] = f2bf(g[i][1].x); r.u[5] = f2bf(g[i][1].y);
      r.u[6] = f2bf(g[i][1].z); r.u[7] = f2bf(g[i][1].w);
      *(bf16x8*)(wbase + (r0 + (i << 5)) * 16) = r.v;
    }
    __syncthreads();

    if (kt + 1 < NK) {
      int ko = ((kt + 1) << 5) + (kslot << 3);
#pragma unroll
      for (int i = 0; i < 4; ++i) {
        const float* p = gbase + (size_t)(gr0 + (i << 5)) * K + ko;
        g[i][0] = *(const float4*)p;
        g[i][1] = *(const float4*)(p + 4);
      }
    }

    bf16x8 af[4], bf[4];
#pragma unroll
    for (int f = 0; f < 4; ++f) {
      af[f] = *(const bf16x8*)(ard + f * 256);
      bf[f] = *(const bf16x8*)(brd + f * 256);
    }
#pragma unroll
    for (int fm = 0; fm < 4; ++fm)
#pragma unroll
      for (int fn = 0; fn < 4; ++fn)
        acc[fm][fn] = __builtin_amdgcn_mfma_f32_16x16x32_bf16(
            af[fm], bf[fn], acc[fm][fn], 0, 0, 0);
  }

  const int orow0 = m0 + wr * 64 + (lk << 2);
  const int ocol0 = n0 + wc * 64 + lr;        // global col in [0,2304)
  const int bcol0 = nloc + wc * 64 + lr;      // col within selected bias
#pragma unroll
  for (int fn = 0; fn < 4; ++fn) {
    int col = ocol0 + fn * 16;
    float bvv = bias[bcol0 + fn * 16];
#pragma unroll
    for (int fm = 0; fm < 4; ++fm) {
#pragma unroll
      for (int j = 0; j < 4; ++j) {
        int row = orow0 + fm * 16 + j;
        C[(size_t)row * NTOT + col] = acc[fm][fn][j] + bvv;
      }
    }
  }
}

// ---------------------------------------------------------------------------
// Tiled flash attention (fp32 VALU). Grid: (T/64, H); block 256 = 4 waves.
// q/k/v read with row stride QS (interleaved [T,2304] buffer); ctx written
// with row stride D.
// ---------------------------------------------------------------------------
__global__ __launch_bounds__(256) void k_flash(const float* __restrict__ q,
                                               const float* __restrict__ k,
                                               const float* __restrict__ v,
                                               float* __restrict__ ctx,
                                               int T, int QS, int D,
                                               float scale) {
  __shared__ float Qs[64][68];   // Q^T: [d][q], pre-scaled
  __shared__ float KPs[64][68];  // K^T: [d][s] during QK; P^T: [s][q] during PV
  __shared__ float Vs[64][68];   // V:   [s][d]
  int tid = threadIdx.x;
  int tx = tid & 15, ty = tid >> 4;
  int qt = gridDim.x - 1 - blockIdx.x;  // big tiles first
  int q0 = qt << 6;
  int hoff = blockIdx.y << 6;

  {
    int row = tid >> 2;
    int col = (tid & 3) << 4;
    const float* src = q + (size_t)(q0 + row) * QS + hoff + col;
#pragma unroll
    for (int i = 0; i < 4; ++i) {
      float4 a = *(const float4*)(src + (i << 2));
      Qs[col + (i << 2) + 0][row] = a.x * scale;
      Qs[col + (i << 2) + 1][row] = a.y * scale;
      Qs[col + (i << 2) + 2][row] = a.z * scale;
      Qs[col + (i << 2) + 3][row] = a.w * scale;
    }
  }

  float m[4] = {-1e30f, -1e30f, -1e30f, -1e30f};
  float l[4] = {0.f, 0.f, 0.f, 0.f};
  float po[4][4] = {};

  for (int st = 0; st <= qt; ++st) {
    int s0 = st << 6;
    __syncthreads();
    {
      int row = tid >> 2;
      int col = (tid & 3) << 4;
      const float* ksrc = k + (size_t)(s0 + row) * QS + hoff + col;
      const float* vsrc = v + (size_t)(s0 + row) * QS + hoff + col;
#pragma unroll
      for (int i = 0; i < 4; ++i) {
        float4 a = *(const float4*)(ksrc + (i << 2));
        KPs[col + (i << 2) + 0][row] = a.x;
        KPs[col + (i << 2) + 1][row] = a.y;
        KPs[col + (i << 2) + 2][row] = a.z;
        KPs[col + (i << 2) + 3][row] = a.w;
        *(float4*)&Vs[row][col + (i << 2)] = *(const float4*)(vsrc + (i << 2));
      }
    }
    __syncthreads();

    float s[4][4] = {};
#pragma unroll 8
    for (int kk = 0; kk < 64; ++kk) {
      float4 a = *(const float4*)&Qs[kk][ty << 2];
      float4 b = *(const float4*)&KPs[kk][tx << 2];
      s[0][0] += a.x * b.x; s[0][1] += a.x * b.y; s[0][2] += a.x * b.z; s[0][3] += a.x * b.w;
      s[1][0] += a.y * b.x; s[1][1] += a.y * b.y; s[1][2] += a.y * b.z; s[1][3] += a.y * b.w;
      s[2][0] += a.z * b.x; s[2][1] += a.z * b.y; s[2][2] += a.z * b.z; s[2][3] += a.z * b.w;
      s[3][0] += a.w * b.x; s[3][1] += a.w * b.y; s[3][2] += a.w * b.z; s[3][3] += a.w * b.w;
    }

    if (st == qt) {
#pragma unroll
      for (int qi = 0; qi < 4; ++qi) {
        int qrow = (ty << 2) + qi;
#pragma unroll
        for (int si = 0; si < 4; ++si) {
          if ((tx << 2) + si > qrow) s[qi][si] = -1e30f;
        }
      }
    }

    float alpha[4];
#pragma unroll
    for (int qi = 0; qi < 4; ++qi) {
      float rmax = fmaxf(fmaxf(s[qi][0], s[qi][1]), fmaxf(s[qi][2], s[qi][3]));
      rmax = fmaxf(rmax, __shfl_xor(rmax, 1, 64));
      rmax = fmaxf(rmax, __shfl_xor(rmax, 2, 64));
      rmax = fmaxf(rmax, __shfl_xor(rmax, 4, 64));
      rmax = fmaxf(rmax, __shfl_xor(rmax, 8, 64));
      float mn = fmaxf(m[qi], rmax);
      alpha[qi] = __expf(m[qi] - mn);
      m[qi] = mn;
      float rsum = 0.f;
#pragma unroll
      for (int si = 0; si < 4; ++si) {
        float p = __expf(s[qi][si] - mn);
        s[qi][si] = p;
        rsum += p;
      }
      rsum += __shfl_xor(rsum, 1, 64);
      rsum += __shfl_xor(rsum, 2, 64);
      rsum += __shfl_xor(rsum, 4, 64);
      rsum += __shfl_xor(rsum, 8, 64);
      l[qi] = l[qi] * alpha[qi] + rsum;
      po[qi][0] *= alpha[qi]; po[qi][1] *= alpha[qi];
      po[qi][2] *= alpha[qi]; po[qi][3] *= alpha[qi];
    }

    __syncthreads();
#pragma unroll
    for (int si = 0; si < 4; ++si) {
      float4 p4 = make_float4(s[0][si], s[1][si], s[2][si], s[3][si]);
      *(float4*)&KPs[(tx << 2) + si][ty << 2] = p4;
    }
    __syncthreads();

#pragma unroll 8
    for (int kk = 0; kk < 64; ++kk) {
      float4 a = *(const float4*)&KPs[kk][ty << 2];
      float4 b = *(const float4*)&Vs[kk][tx << 2];
      po[0][0] += a.x * b.x; po[0][1] += a.x * b.y; po[0][2] += a.x * b.z; po[0][3] += a.x * b.w;
      po[1][0] += a.y * b.x; po[1][1] += a.y * b.y; po[1][2] += a.y * b.z; po[1][3] += a.y * b.w;
      po[2][0] += a.z * b.x; po[2][1] += a.z * b.y; po[2][2] += a.z * b.z; po[2][3] += a.z * b.w;
      po[3][0] += a.w * b.x; po[3][1] += a.w * b.y; po[3][2] += a.w * b.z; po[3][3] += a.w * b.w;
    }
  }

#pragma unroll
  for (int qi = 0; qi < 4; ++qi) {
    float inv = 1.0f / l[qi];
    float4 r = make_float4(po[qi][0] * inv, po[qi][1] * inv,
                           po[qi][2] * inv, po[qi][3] * inv);
    *(float4*)(ctx + (size_t)(q0 + (ty << 2) + qi) * D + hoff + (tx << 2)) = r;
  }
}

extern "C" void kernel_launch(void* const* d_in, const int* in_sizes, int n_in,
                              void* d_out, int out_size, void* d_ws, size_t ws_size,
                              hipStream_t stream) {
  const int T = 2048, D = 768, H = 12, L = 4, V = 50257, D4 = 3072;
  const size_t td = (size_t)T * D;

  const int* ids      = (const int*)d_in[0];
  const float* emb    = (const float*)d_in[1];
  const float* lm_bias= (const float*)d_in[2];
  const float* ln1_g  = (const float*)d_in[3];
  const float* ln1_b  = (const float*)d_in[4];
  const float* ln2_g  = (const float*)d_in[5];
  const float* ln2_b  = (const float*)d_in[6];
  const float* Wq     = (const float*)d_in[7];
  const float* bq     = (const float*)d_in[8];
  const float* Wk     = (const float*)d_in[9];
  const float* bk     = (const float*)d_in[10];
  const float* Wv     = (const float*)d_in[11];
  const float* bv     = (const float*)d_in[12];
  const float* Wo     = (const float*)d_in[13];
  const float* bo     = (const float*)d_in[14];
  const float* W1     = (const float*)d_in[15];
  const float* b1     = (const float*)d_in[16];
  const float* W2     = (const float*)d_in[17];
  const float* b2     = (const float*)d_in[18];
  const float* lnf_g  = (const float*)d_in[19];
  const float* lnf_b  = (const float*)d_in[20];
  float* out = (float*)d_out;

  // Scratch layout:
  //   x, xn        -> d_ws (2*T*D fp32 = 12.6 MB; ws always holds these)
  //   qkv/ctx/MLP  -> d_ws if it fits 6*T*D fp32 (37.75 MB); otherwise the
  //                   FRONT of d_out (4*T*D fp32 = 25.2 MB << out buffer),
  //                   dead before the LM-head GEMM (sole writer of out;
  //                   reads xn in d_ws and emb).
  //   qkvb = [T,2304] interleaved q|k|v (3*td), cb = [T,768] ctx (1*td),
  //   hb   = [T,3072] MLP hidden, aliases qkvb+cb (dead during MLP).
  float* x  = (float*)d_ws;
  float* xn = x + td;
  float* qkvb;
  if (ws_size >= (size_t)6 * td * sizeof(float)) {
    qkvb = xn + td;
  } else {
    qkvb = out;  // front of d_out
  }
  float* cb = qkvb + 3 * td;
  float* hb = qkvb;  // [T, 4D]

  dim3 blk(256);
  k_embed<<<T, blk, 0, stream>>>(ids, emb, x, T, D);

  for (int l = 0; l < L; ++l) {
    k_layernorm<<<T, blk, 0, stream>>>(x, ln1_g + l * D, ln1_b + l * D, xn, D);

    // fused QKV: [T,2304] = xn @ [Wq|Wk|Wv]^T + biases
    k_mmqkv<<<18 * (T / 128), blk, 0, stream>>>(
        xn, Wq + (size_t)l * D * D, Wk + (size_t)l * D * D, Wv + (size_t)l * D * D,
        bq + l * D, bk + l * D, bv + l * D, qkvb, T, D);

    dim3 ga(T / 64, H);
    k_flash<<<ga, blk, 0, stream>>>(qkvb, qkvb + 768, qkvb + 1536, cb,
                                    T, 2304, D, 0.125f);

    k_mm<<<(D / 128) * (T / 128), blk, 0, stream>>>(
        cb, Wo + (size_t)l * D * D, bo + l * D, x, x, T, D, D, 1);

    k_layernorm<<<T, blk, 0, stream>>>(x, ln2_g + l * D, ln2_b + l * D, xn, D);

    k_mm<<<(D4 / 128) * (T / 128), blk, 0, stream>>>(
        xn, W1 + (size_t)l * D4 * D, b1 + l * D4, nullptr, hb, T, D4, D, 2);

    k_mm<<<(D / 128) * (T / 128), blk, 0, stream>>>(
        hb, W2 + (size_t)l * D * D4, b2 + l * D, x, x, T, D, D4, 1);
  }

  k_layernorm<<<T, blk, 0, stream>>>(x, lnf_g, lnf_b, xn, D);

  k_mm<<<((V + 127) / 128) * (T / 128), blk, 0, stream>>>(
      xn, emb, lm_bias, nullptr, out, T, V, D, 0);
}

// Round 6
// 2723.658 us; speedup vs baseline: 5.0581x; 1.1364x over previous
//
#include <hip/hip_runtime.h>
#include <hip/hip_bf16.h>
#include <math.h>

// ---------------------------------------------------------------------------
// GPT-style transformer forward. Round 6: bf16 weight pool + double-buffered
// bf16 GEMM pipeline.
// L=4, H=12, HD=64, D=768, V=50257, B=1, T=2048
// Round-5 profile: k_mm latency-bound (MfmaUtil 12%, VALU 23%, HBM 45%,
// occ 33% -- nothing saturated). Per-K-step serialization: stage -> barrier
// -> 16 MFMA (~80cy) -> stall on next loads (~200-900cy), plus fp32->bf16
// conversion VALU in every staging step of every block.
// Fixes: (1) pre-cast weights to bf16 pool once (front of d_out, dead before
// LM head); Wq|Wk|Wv concatenated -> QKV is a plain k_mm, N=2304.
// (2) producers (LN, flash, gelu) emit bf16 A-inputs -- identical rounding to
// what the consumer GEMM did before, numerics unchanged vs round 5.
// (3) k_mm double-buffered: loads(t+1) issue -> MFMA(t) -> LDS write(t+1) ->
// single barrier; load latency hidden behind compute. LM head keeps fp32-B
// on-the-fly conversion (emb has no safe bf16 home), A is bf16.
// ---------------------------------------------------------------------------

typedef __attribute__((ext_vector_type(8))) short bf16x8;
typedef __attribute__((ext_vector_type(4))) float f32x4;
typedef unsigned short u16;

// bf16 weight-pool layout (elems per layer): [qkv 2304x768][o 768x768]
// [w1 3072x768][w2 768x3072]
constexpr int OSZ   = 589824;        // 768*768
constexpr int QKVSZ = 3 * OSZ;       // 1769472
constexpr int W1SZ  = 2359296;       // 3072*768
constexpr int PER_L = QKVSZ + OSZ + W1SZ + W1SZ;  // 7077888

__device__ __forceinline__ u16 f2bf(float f) {
  unsigned u = __float_as_uint(f);
  u += 0x7FFFu + ((u >> 16) & 1u);
  return (u16)(u >> 16);
}

__device__ __forceinline__ float gelu_exact(float v) {
  return 0.5f * v * (1.0f + erff(v * 0.70710678118654752f));
}

// Bijective XCD swizzle (m204): contiguous logical chunk per XCD.
__device__ __forceinline__ int xcd_swizzle(int orig, int nwg) {
  int xcd = orig & 7, lid = orig >> 3;
  int q8 = nwg >> 3, r8 = nwg & 7;
  return (xcd < r8 ? xcd * (q8 + 1) : r8 * (q8 + 1) + (xcd - r8) * q8) + lid;
}

__global__ __launch_bounds__(256) void k_embed(const int* __restrict__ ids,
                                               const float* __restrict__ emb,
                                               float* __restrict__ x,
                                               int T, int D) {
  int t = blockIdx.x;
  int id = ids[t];
  float neg_log = -logf(10000.0f) / (float)D;
  for (int d = threadIdx.x; d < D; d += 256) {
    float freq = expf((float)(d & ~1) * neg_log);
    float ang = (float)t * freq;
    float pe = (d & 1) ? cosf(ang) : sinf(ang);
    x[(size_t)t * D + d] = emb[(size_t)id * D + d] + pe;
  }
}

// LayerNorm, bf16 output (same rounding the consumer GEMM applied before).
__global__ __launch_bounds__(256) void k_layernorm(const float* __restrict__ x,
                                                   const float* __restrict__ g,
                                                   const float* __restrict__ b,
                                                   u16* __restrict__ y,
                                                   int D) {
  int t = blockIdx.x;
  const float* xr = x + (size_t)t * D;
  __shared__ float red[256];
  float s = 0.f;
  for (int d = threadIdx.x; d < D; d += 256) s += xr[d];
  red[threadIdx.x] = s;
  __syncthreads();
  for (int st = 128; st > 0; st >>= 1) {
    if (threadIdx.x < st) red[threadIdx.x] += red[threadIdx.x + st];
    __syncthreads();
  }
  float mean = red[0] / (float)D;
  __syncthreads();
  float s2 = 0.f;
  for (int d = threadIdx.x; d < D; d += 256) {
    float u = xr[d] - mean;
    s2 += u * u;
  }
  red[threadIdx.x] = s2;
  __syncthreads();
  for (int st = 128; st > 0; st >>= 1) {
    if (threadIdx.x < st) red[threadIdx.x] += red[threadIdx.x + st];
    __syncthreads();
  }
  float rstd = rsqrtf(red[0] / (float)D + 1e-5f);
  u16* yr = y + (size_t)t * D;
  for (int d = threadIdx.x; d < D; d += 256)
    yr[d] = f2bf((xr[d] - mean) * rstd * g[d] + b[d]);
}

// One-time weight cast: fp32 inputs -> bf16 pool (layout above). 8 elems/thr.
__global__ __launch_bounds__(256) void k_castw(const float* __restrict__ Wq,
                                               const float* __restrict__ Wk,
                                               const float* __restrict__ Wv,
                                               const float* __restrict__ Wo,
                                               const float* __restrict__ W1,
                                               const float* __restrict__ W2,
                                               u16* __restrict__ pool) {
  unsigned i8 = (blockIdx.x * 256u + threadIdx.x) * 8u;   // < 28.3M, fits u32
  unsigned l = i8 / (unsigned)PER_L;
  unsigned off = i8 - l * (unsigned)PER_L;
  const float* src;
  if (off < (unsigned)QKVSZ) {
    unsigned w = off / (unsigned)OSZ;
    unsigned o = off - w * (unsigned)OSZ;
    src = (w == 0 ? Wq : (w == 1 ? Wk : Wv)) + (size_t)l * OSZ + o;
  } else if (off < (unsigned)(QKVSZ + OSZ)) {
    src = Wo + (size_t)l * OSZ + (off - QKVSZ);
  } else if (off < (unsigned)(QKVSZ + OSZ + W1SZ)) {
    src = W1 + (size_t)l * W1SZ + (off - (QKVSZ + OSZ));
  } else {
    src = W2 + (size_t)l * W1SZ + (off - (QKVSZ + OSZ + W1SZ));
  }
  float4 a = *(const float4*)src;
  float4 b = *(const float4*)(src + 4);
  union { bf16x8 v; u16 u[8]; } r;
  r.u[0] = f2bf(a.x); r.u[1] = f2bf(a.y); r.u[2] = f2bf(a.z); r.u[3] = f2bf(a.w);
  r.u[4] = f2bf(b.x); r.u[5] = f2bf(b.y); r.u[6] = f2bf(b.z); r.u[7] = f2bf(b.w);
  *(bf16x8*)(pool + i8) = r.v;
}

// Concatenated QKV bias: bqkv[l][0:768]=bq, [768:1536]=bk, [1536:2304]=bv.
__global__ __launch_bounds__(256) void k_castb(const float* __restrict__ bq,
                                               const float* __restrict__ bk,
                                               const float* __restrict__ bv,
                                               float* __restrict__ bqkv) {
  for (int i = threadIdx.x; i < 4 * 2304; i += 256) {
    int l = i / 2304, c = i - l * 2304;
    int w = c / 768, cc = c - w * 768;
    bqkv[i] = (w == 0 ? bq : (w == 1 ? bk : bv))[l * 768 + cc];
  }
}

// ---------------------------------------------------------------------------
// C[M,N] = A[M,K] @ B[N,K]^T + bias[N]
// A: bf16. B: bf16 (bfB=1) or fp32 (bfB=0, converted in staging -- LM head).
// mode 0: bias, fp32 C; mode 1: bias+res, fp32 C; mode 2: gelu, bf16 C.
// 128x128 tile, BK=32, 4 waves (64x64 quadrant each), mfma 16x16x32 bf16.
// Double-buffered LDS (2 x 16.6 KB): per K-step issue loads(t+1) -> ds_read +
// 16 MFMA on buf[cur] -> LDS write(t+1) into buf[cur^1] -> one barrier.
// PLANE padded (+32B) => conflict-light ds_write_b128/ds_read_b128.
// ---------------------------------------------------------------------------
__global__ __launch_bounds__(256) void k_mm(const u16* __restrict__ A,
                                            const void* __restrict__ Bv,
                                            const float* __restrict__ bias,
                                            const float* __restrict__ res,
                                            void* __restrict__ Cv,
                                            int M, int N, int K,
                                            int mode, int bfB) {
  constexpr int PLANE = 2080;      // 128 rows * 16 B + 32 pad
  constexpr int MATS  = 4 * PLANE; // per matrix per buffer (8320 B)
  constexpr int BUFSZ = 2 * MATS;  // A+B per buffer (16640 B)
  __shared__ alignas(16) unsigned char smem[2 * BUFSZ];

  const int nbx = (N + 127) >> 7;
  const int nby = M >> 7;
  const int swz = xcd_swizzle(blockIdx.x, nbx * nby);
  const int nb = swz / nby;        // n panel major
  const int mb = swz - nb * nby;   // m fastest
  const int m0 = mb << 7, n0 = nb << 7;

  const int tid = threadIdx.x;
  const int lane = tid & 63;
  const int wid = tid >> 6;
  const int wr = wid >> 1, wc = wid & 1;

  const int mat = tid >> 7;        // 0: stage A, 1: stage B
  const int ts = tid & 127;
  const int kslot = ts & 3;        // 16B slot within a row's 64 B
  const int r0 = ts >> 2;          // rows r0 + {0,32,64,96}
  const int gr0 = (mat ? n0 : m0) + r0;
  const bool srcbf = (mat == 0) || (bfB != 0);
  const u16* gbf = mat ? (const u16*)Bv : A;
  const float* gf32 = (const float*)Bv;
  unsigned char* wb0 = smem + mat * MATS + kslot * PLANE;

  const int lr = lane & 15, lk = lane >> 4;
  const int ardo = lk * PLANE + (wr * 64 + lr) * 16;
  const int brdo = MATS + lk * PLANE + (wc * 64 + lr) * 16;

  f32x4 acc[4][4] = {};
  float4 rg[4][2];  // staging regs; bf16 path uses rg[i][0] as raw 16 B

  const int NK = K >> 5;

  auto LOAD = [&](int kt) {
    const int ko = (kt << 5) + (kslot << 3);
    if (srcbf) {
#pragma unroll
      for (int i = 0; i < 4; ++i) {
        int grow = gr0 + (i << 5);
        if (mat == 0 || grow < N)
          rg[i][0] = *(const float4*)(gbf + (size_t)grow * K + ko);
        else
          rg[i][0] = make_float4(0.f, 0.f, 0.f, 0.f);
      }
    } else {
#pragma unroll
      for (int i = 0; i < 4; ++i) {
        int grow = gr0 + (i << 5);
        if (grow < N) {
          const float* p = gf32 + (size_t)grow * K + ko;
          rg[i][0] = *(const float4*)p;
          rg[i][1] = *(const float4*)(p + 4);
        } else {
          rg[i][0] = make_float4(0.f, 0.f, 0.f, 0.f);
          rg[i][1] = make_float4(0.f, 0.f, 0.f, 0.f);
        }
      }
    }
  };
  auto STORE = [&](int buf) {
    unsigned char* wb = wb0 + buf * BUFSZ;
    if (srcbf) {
#pragma unroll
      for (int i = 0; i < 4; ++i)
        *(float4*)(wb + (r0 + (i << 5)) * 16) = rg[i][0];
    } else {
#pragma unroll
      for (int i = 0; i < 4; ++i) {
        union { bf16x8 v; u16 u[8]; } r;
        r.u[0] = f2bf(rg[i][0].x); r.u[1] = f2bf(rg[i][0].y);
        r.u[2] = f2bf(rg[i][0].z); r.u[3] = f2bf(rg[i][0].w);
        r.u[4] = f2bf(rg[i][1].x); r.u[5] = f2bf(rg[i][1].y);
        r.u[6] = f2bf(rg[i][1].z); r.u[7] = f2bf(rg[i][1].w);
        *(bf16x8*)(wb + (r0 + (i << 5)) * 16) = r.v;
      }
    }
  };

  LOAD(0);
  STORE(0);
  __syncthreads();
  int cur = 0;

  for (int kt = 0; kt < NK; ++kt) {
    if (kt + 1 < NK) LOAD(kt + 1);   // issue next-tile loads before compute
    const unsigned char* base = smem + cur * BUFSZ;
    bf16x8 af[4], bfr[4];
#pragma unroll
    for (int f = 0; f < 4; ++f) {
      af[f]  = *(const bf16x8*)(base + ardo + f * 256);
      bfr[f] = *(const bf16x8*)(base + brdo + f * 256);
    }
#pragma unroll
    for (int fm = 0; fm < 4; ++fm)
#pragma unroll
      for (int fn = 0; fn < 4; ++fn)
        acc[fm][fn] = __builtin_amdgcn_mfma_f32_16x16x32_bf16(
            af[fm], bfr[fn], acc[fm][fn], 0, 0, 0);
    if (kt + 1 < NK) {
      STORE(cur ^ 1);   // waits vmcnt here, hidden behind the MFMAs above
      __syncthreads();
      cur ^= 1;
    }
  }

  // epilogue: C/D layout col = lane&15, row = (lane>>4)*4 + reg
  const int orow0 = m0 + wr * 64 + (lk << 2);
  const int ocol0 = n0 + wc * 64 + lr;
  if (mode == 2) {
    u16* C = (u16*)Cv;
#pragma unroll
    for (int fn = 0; fn < 4; ++fn) {
      int col = ocol0 + fn * 16;
      if (col >= N) continue;
      float bv = bias[col];
#pragma unroll
      for (int fm = 0; fm < 4; ++fm)
#pragma unroll
        for (int j = 0; j < 4; ++j) {
          int row = orow0 + fm * 16 + j;
          C[(size_t)row * N + col] = f2bf(gelu_exact(acc[fm][fn][j] + bv));
        }
    }
  } else {
    float* C = (float*)Cv;
#pragma unroll
    for (int fn = 0; fn < 4; ++fn) {
      int col = ocol0 + fn * 16;
      if (col >= N) continue;
      float bv = bias[col];
#pragma unroll
      for (int fm = 0; fm < 4; ++fm)
#pragma unroll
        for (int j = 0; j < 4; ++j) {
          int row = orow0 + fm * 16 + j;
          float vvv = acc[fm][fn][j] + bv;
          if (mode == 1) vvv += res[(size_t)row * N + col];
          C[(size_t)row * N + col] = vvv;
        }
    }
  }
}

// ---------------------------------------------------------------------------
// Tiled flash attention (fp32 VALU). Grid: (T/64, H); block 256 = 4 waves.
// q/k/v fp32 with row stride QS (interleaved [T,2304]); ctx written bf16
// with row stride D (same rounding the Wo GEMM applied before).
// ---------------------------------------------------------------------------
__global__ __launch_bounds__(256) void k_flash(const float* __restrict__ q,
                                               const float* __restrict__ k,
                                               const float* __restrict__ v,
                                               u16* __restrict__ ctx,
                                               int T, int QS, int D,
                                               float scale) {
  __shared__ float Qs[64][68];   // Q^T: [d][q], pre-scaled
  __shared__ float KPs[64][68];  // K^T during QK; P^T during PV
  __shared__ float Vs[64][68];   // V: [s][d]
  int tid = threadIdx.x;
  int tx = tid & 15, ty = tid >> 4;
  int qt = gridDim.x - 1 - blockIdx.x;  // big tiles first
  int q0 = qt << 6;
  int hoff = blockIdx.y << 6;

  {
    int row = tid >> 2;
    int col = (tid & 3) << 4;
    const float* src = q + (size_t)(q0 + row) * QS + hoff + col;
#pragma unroll
    for (int i = 0; i < 4; ++i) {
      float4 a = *(const float4*)(src + (i << 2));
      Qs[col + (i << 2) + 0][row] = a.x * scale;
      Qs[col + (i << 2) + 1][row] = a.y * scale;
      Qs[col + (i << 2) + 2][row] = a.z * scale;
      Qs[col + (i << 2) + 3][row] = a.w * scale;
    }
  }

  float m[4] = {-1e30f, -1e30f, -1e30f, -1e30f};
  float l[4] = {0.f, 0.f, 0.f, 0.f};
  float po[4][4] = {};

  for (int st = 0; st <= qt; ++st) {
    int s0 = st << 6;
    __syncthreads();
    {
      int row = tid >> 2;
      int col = (tid & 3) << 4;
      const float* ksrc = k + (size_t)(s0 + row) * QS + hoff + col;
      const float* vsrc = v + (size_t)(s0 + row) * QS + hoff + col;
#pragma unroll
      for (int i = 0; i < 4; ++i) {
        float4 a = *(const float4*)(ksrc + (i << 2));
        KPs[col + (i << 2) + 0][row] = a.x;
        KPs[col + (i << 2) + 1][row] = a.y;
        KPs[col + (i << 2) + 2][row] = a.z;
        KPs[col + (i << 2) + 3][row] = a.w;
        *(float4*)&Vs[row][col + (i << 2)] = *(const float4*)(vsrc + (i << 2));
      }
    }
    __syncthreads();

    float s[4][4] = {};
#pragma unroll 8
    for (int kk = 0; kk < 64; ++kk) {
      float4 a = *(const float4*)&Qs[kk][ty << 2];
      float4 b = *(const float4*)&KPs[kk][tx << 2];
      s[0][0] += a.x * b.x; s[0][1] += a.x * b.y; s[0][2] += a.x * b.z; s[0][3] += a.x * b.w;
      s[1][0] += a.y * b.x; s[1][1] += a.y * b.y; s[1][2] += a.y * b.z; s[1][3] += a.y * b.w;
      s[2][0] += a.z * b.x; s[2][1] += a.z * b.y; s[2][2] += a.z * b.z; s[2][3] += a.z * b.w;
      s[3][0] += a.w * b.x; s[3][1] += a.w * b.y; s[3][2] += a.w * b.z; s[3][3] += a.w * b.w;
    }

    if (st == qt) {
#pragma unroll
      for (int qi = 0; qi < 4; ++qi) {
        int qrow = (ty << 2) + qi;
#pragma unroll
        for (int si = 0; si < 4; ++si) {
          if ((tx << 2) + si > qrow) s[qi][si] = -1e30f;
        }
      }
    }

    float alpha[4];
#pragma unroll
    for (int qi = 0; qi < 4; ++qi) {
      float rmax = fmaxf(fmaxf(s[qi][0], s[qi][1]), fmaxf(s[qi][2], s[qi][3]));
      rmax = fmaxf(rmax, __shfl_xor(rmax, 1, 64));
      rmax = fmaxf(rmax, __shfl_xor(rmax, 2, 64));
      rmax = fmaxf(rmax, __shfl_xor(rmax, 4, 64));
      rmax = fmaxf(rmax, __shfl_xor(rmax, 8, 64));
      float mn = fmaxf(m[qi], rmax);
      alpha[qi] = __expf(m[qi] - mn);
      m[qi] = mn;
      float rsum = 0.f;
#pragma unroll
      for (int si = 0; si < 4; ++si) {
        float p = __expf(s[qi][si] - mn);
        s[qi][si] = p;
        rsum += p;
      }
      rsum += __shfl_xor(rsum, 1, 64);
      rsum += __shfl_xor(rsum, 2, 64);
      rsum += __shfl_xor(rsum, 4, 64);
      rsum += __shfl_xor(rsum, 8, 64);
      l[qi] = l[qi] * alpha[qi] + rsum;
      po[qi][0] *= alpha[qi]; po[qi][1] *= alpha[qi];
      po[qi][2] *= alpha[qi]; po[qi][3] *= alpha[qi];
    }

    __syncthreads();
#pragma unroll
    for (int si = 0; si < 4; ++si) {
      float4 p4 = make_float4(s[0][si], s[1][si], s[2][si], s[3][si]);
      *(float4*)&KPs[(tx << 2) + si][ty << 2] = p4;
    }
    __syncthreads();

#pragma unroll 8
    for (int kk = 0; kk < 64; ++kk) {
      float4 a = *(const float4*)&KPs[kk][ty << 2];
      float4 b = *(const float4*)&Vs[kk][tx << 2];
      po[0][0] += a.x * b.x; po[0][1] += a.x * b.y; po[0][2] += a.x * b.z; po[0][3] += a.x * b.w;
      po[1][0] += a.y * b.x; po[1][1] += a.y * b.y; po[1][2] += a.y * b.z; po[1][3] += a.y * b.w;
      po[2][0] += a.z * b.x; po[2][1] += a.z * b.y; po[2][2] += a.z * b.z; po[2][3] += a.z * b.w;
      po[3][0] += a.w * b.x; po[3][1] += a.w * b.y; po[3][2] += a.w * b.z; po[3][3] += a.w * b.w;
    }
  }

#pragma unroll
  for (int qi = 0; qi < 4; ++qi) {
    float inv = 1.0f / l[qi];
    ushort4 r;
    r.x = f2bf(po[qi][0] * inv); r.y = f2bf(po[qi][1] * inv);
    r.z = f2bf(po[qi][2] * inv); r.w = f2bf(po[qi][3] * inv);
    *(ushort4*)(ctx + (size_t)(q0 + (ty << 2) + qi) * D + hoff + (tx << 2)) = r;
  }
}

extern "C" void kernel_launch(void* const* d_in, const int* in_sizes, int n_in,
                              void* d_out, int out_size, void* d_ws, size_t ws_size,
                              hipStream_t stream) {
  const int T = 2048, D = 768, H = 12, L = 4, V = 50257, D4 = 3072;
  const size_t td = (size_t)T * D;

  const int* ids      = (const int*)d_in[0];
  const float* emb    = (const float*)d_in[1];
  const float* lm_bias= (const float*)d_in[2];
  const float* ln1_g  = (const float*)d_in[3];
  const float* ln1_b  = (const float*)d_in[4];
  const float* ln2_g  = (const float*)d_in[5];
  const float* ln2_b  = (const float*)d_in[6];
  const float* Wq     = (const float*)d_in[7];
  const float* bq     = (const float*)d_in[8];
  const float* Wk     = (const float*)d_in[9];
  const float* bk     = (const float*)d_in[10];
  const float* Wv     = (const float*)d_in[11];
  const float* bv     = (const float*)d_in[12];
  const float* Wo     = (const float*)d_in[13];
  const float* bo     = (const float*)d_in[14];
  const float* W1     = (const float*)d_in[15];
  const float* b1     = (const float*)d_in[16];
  const float* W2     = (const float*)d_in[17];
  const float* b2     = (const float*)d_in[18];
  const float* lnf_g  = (const float*)d_in[19];
  const float* lnf_b  = (const float*)d_in[20];
  float* out = (float*)d_out;

  // Scratch:
  //   d_ws  (>=12.6 MB, proven by rounds 0-5): x fp32 [T,768] + xnb bf16
  //         [T,768]  (9.4 MB). xnb shared by LN1/LN2/LNf outputs (disjoint
  //         lifetimes). LM head reads ONLY xnb (ws) + emb/lm_bias (inputs).
  //   d_out front (~91 MB of 412 MB), all dead before the LM-head GEMM:
  //         wpool bf16 weights (56.6 MB) | bqkv fp32 (36 KB) |
  //         qkv fp32 [T,2304] (18.9 MB) | cbb bf16 [T,768] (3.1 MB) |
  //         hbb bf16 [T,3072] (12.6 MB)
  float* x  = (float*)d_ws;
  u16* xnb  = (u16*)(x + td);

  char* cur = (char*)d_out;
  u16* wpool = (u16*)cur;  cur += (size_t)4 * PER_L * 2;
  float* bqkv = (float*)cur; cur += (size_t)4 * 2304 * 4;
  float* qkv = (float*)cur;  cur += (size_t)3 * td * 4;
  u16* cbb = (u16*)cur;      cur += td * 2;
  u16* hbb = (u16*)cur;      // + T*D4*2

  dim3 blk(256);

  // one-time casts (per launch): ~134 MB traffic ≈ 25 us
  k_castw<<<(4 * PER_L) / (256 * 8), blk, 0, stream>>>(Wq, Wk, Wv, Wo, W1, W2, wpool);
  k_castb<<<1, blk, 0, stream>>>(bq, bk, bv, bqkv);

  k_embed<<<T, blk, 0, stream>>>(ids, emb, x, T, D);

  for (int l = 0; l < L; ++l) {
    const u16* wl = wpool + (size_t)l * PER_L;

    k_layernorm<<<T, blk, 0, stream>>>(x, ln1_g + l * D, ln1_b + l * D, xnb, D);

    // fused QKV via concatenated weights: [T,2304]
    k_mm<<<18 * 16, blk, 0, stream>>>(xnb, wl, bqkv + l * 2304, nullptr,
                                      qkv, T, 2304, 768, 0, 1);

    dim3 ga(T / 64, H);
    k_flash<<<ga, blk, 0, stream>>>(qkv, qkv + 768, qkv + 1536, cbb,
                                    T, 2304, D, 0.125f);

    k_mm<<<6 * 16, blk, 0, stream>>>(cbb, wl + QKVSZ, bo + l * D, x,
                                     x, T, 768, 768, 1, 1);

    k_layernorm<<<T, blk, 0, stream>>>(x, ln2_g + l * D, ln2_b + l * D, xnb, D);

    k_mm<<<24 * 16, blk, 0, stream>>>(xnb, wl + QKVSZ + OSZ, b1 + l * D4, nullptr,
                                      hbb, T, 3072, 768, 2, 1);

    k_mm<<<6 * 16, blk, 0, stream>>>(hbb, wl + QKVSZ + OSZ + W1SZ, b2 + l * D, x,
                                     x, T, 768, 3072, 1, 1);
  }

  k_layernorm<<<T, blk, 0, stream>>>(x, lnf_g, lnf_b, xnb, D);

  // LM head: A bf16 (ws), B = emb fp32 converted in staging, writes all of out
  k_mm<<<((V + 127) / 128) * 16, blk, 0, stream>>>(xnb, emb, lm_bias, nullptr,
                                                   out, T, V, 768, 0, 0);
}